// Round 11
// baseline (126.939 us; speedup 1.0000x reference)
//
#include <hip/hip_runtime.h>
#include <hip/hip_fp16.h>

#define CIN   32
#define COUT  64
#define TT    8
#define HH    56
#define WW    56
#define KK    27
#define SP    (TT * HH * WW)   // 25088
#define NB    2
#define NBLK  784              // (NB*SP)/64
#define KSPLIT 14              // waves 0-3: taps [0,14)+bias; waves 4-7: [14,27)

typedef __attribute__((ext_vector_type(8))) _Float16 half8;
typedef __attribute__((ext_vector_type(4))) float    f32x4;

// d_ws layout
#define WF_OFF   0                    // weight A-frags (16x16x32): 110,592 B
#define XTH_OFF  (128 << 10)          // xTh fp16 channel-last: 3,211,264 B

// prep: blocks [0,784): x [N][C][SP] fp32 -> xTh [N][SP][C] fp16
//       blocks [784,811): weight -> 16x16x32 A-fragments
//       wf[k][ct][lane][j] = w[co = ct*16 + (lane&15)][c = (lane>>4)*8 + j][k]
__global__ __launch_bounds__(256) void prep_kernel(const float* __restrict__ x,
                                                   const float* __restrict__ w,
                                                   __half* __restrict__ xTh,
                                                   __half* __restrict__ wf) {
    const int b = blockIdx.x;
    const int t = threadIdx.x;
    if (b < NBLK) {
        __shared__ float sm[CIN][65];
        const int s0 = b * 64, n = s0 / SP, sp0 = s0 % SP;
#pragma unroll
        for (int it = 0; it < 8; ++it) {
            const int idx = it * 256 + t, c = idx >> 6, l = idx & 63;
            sm[c][l] = x[((size_t)n * CIN + c) * SP + sp0 + l];
        }
        __syncthreads();
#pragma unroll
        for (int it = 0; it < 4; ++it) {
            const int idx = it * 256 + t, l = idx >> 4, cp = idx & 15;
            ((__half2*)xTh)[((size_t)n * SP + sp0 + l) * (CIN / 2) + cp] =
                __floats2half2_rn(sm[2 * cp][l], sm[2 * cp + 1][l]);
        }
    } else {
        const int k = b - NBLK;        // 2048 elements: [ct(4)][lane(64)][j(8)]
#pragma unroll
        for (int it = 0; it < 8; ++it) {
            const int idx  = it * 256 + t;
            const int j    = idx & 7;
            const int lane = (idx >> 3) & 63;
            const int ct   = (idx >> 9) & 3;
            const int co   = ct * 16 + (lane & 15);
            const int c    = (lane >> 4) * 8 + j;
            wf[(((size_t)k * 4 + ct) * 64 + lane) * 8 + j] =
                __float2half(w[((size_t)co * CIN + c) * KK + k]);
        }
    }
}

// 512-thread blocks: 8 waves = 4 position-tiles x 2 tap-halves.
// Taps processed in PAIRS: both gather sets in flight together (2x MLP).
// Offsets LDS-staged; gathers quad-aligned; bpermute B-frag repack.
__global__ __launch_bounds__(512, 4) void dconv3d_kernel(const __half* __restrict__ xTh,
                                                         const float* __restrict__ off,
                                                         const __half* __restrict__ wf,
                                                         const float* __restrict__ bias,
                                                         float* __restrict__ out) {
    // 20.7 KB: offsets [81][64] during main loop; combine [16][4][64] at end
    __shared__ __align__(16) char smem[81 * 64 * 4];
    float (*offs)[64] = reinterpret_cast<float(*)[64]>(smem);
    float (*cmb)[4][64] = reinterpret_cast<float(*)[4][64]>(smem);

    const int t    = threadIdx.x;
    const int lane = t & 63;
    const int wv   = t >> 6;           // 0..7
    const int wpos = wv & 3;           // position-tile (16 positions each)
    const int half = wv >> 2;          // 0: taps [0,14)+bias, 1: taps [14,27)

    // interp persona (quad-aligned gathers)
    const int posI = lane >> 2;        // 0..15
    const int cgI  = lane & 3;         // channels cgI*8 .. +7
    // gemm persona (MFMA B/C fixed layout)
    const int jg   = lane >> 4;        // B k-group / C row-group

    // bpermute source lane: src = 4*(lane&15) + (lane>>4); byte addr = src*4
    const int bp_addr = (((lane & 15) << 2) | jg) << 2;

    // XCD-aware swizzle (bijective on 784; 392*64 == SP so no batch crossing)
    const int sb  = (blockIdx.x & 7) * 98 + (blockIdx.x >> 3);
    const int s0  = sb * 64;
    const int n   = s0 / SP;
    const int spb = s0 % SP;

    // ---- stage offsets: off[n][row][spb..spb+64) -> offs[row][0..64)
    {
        const float* offbase = off + ((size_t)n * (3 * KK)) * SP + spb;
        for (int i = t; i < 81 * 16; i += 512) {
            const int row = i >> 4, q = i & 15;
            *(float4*)&offs[row][q * 4] = *(const float4*)(offbase + (size_t)row * SP + q * 4);
        }
    }
    __syncthreads();

    const int sp = spb + wpos * 16 + posI;
    const int to = sp / (HH * WW);
    const int hw = sp % (HH * WW);
    const int ho = hw / WW;
    const int wo = hw % WW;
    const int pl = wpos * 16 + posI;   // local position index 0..63

    // bias rides in the MFMA C operand (half 0 only)
    f32x4 acc[4];
#pragma unroll
    for (int ct = 0; ct < 4; ++ct)
#pragma unroll
        for (int r = 0; r < 4; ++r)
            acc[ct][r] = half ? 0.f : bias[ct * 16 + jg * 4 + r];

    const __half* xn = xTh + (size_t)n * SP * CIN;

    // compute addresses + trilinear corner weights for tap k
    auto tap_prep = [&](int k, int* a, float* cw) {
        const int kt  = k / 9;
        const int khh = (k / 3) % 3;
        const int kww = k % 3;

        const float pt_ = (float)(to - 1 + kt)  + offs[k * 3 + 0][pl];
        const float ph_ = (float)(ho - 1 + khh) + offs[k * 3 + 1][pl];
        const float pw_ = (float)(wo - 1 + kww) + offs[k * 3 + 2][pl];

        const float ft = floorf(pt_), fh = floorf(ph_), fw = floorf(pw_);
        const float lt = pt_ - ft, lh = ph_ - fh, lw = pw_ - fw;
        const int t0 = (int)ft, h0 = (int)fh, w0 = (int)fw;
        const int t1 = t0 + 1, h1 = h0 + 1, w1 = w0 + 1;

        float awt[2], awh[2], aww[2];
        int   it2[2], ih2[2], iw2[2];
        awt[0] = (t0 >= 0 && t0 < TT) ? (1.f - lt) : 0.f;
        awt[1] = (t1 >= 0 && t1 < TT) ? lt : 0.f;
        it2[0] = min(max(t0, 0), TT - 1);  it2[1] = min(max(t1, 0), TT - 1);
        awh[0] = (h0 >= 0 && h0 < HH) ? (1.f - lh) : 0.f;
        awh[1] = (h1 >= 0 && h1 < HH) ? lh : 0.f;
        ih2[0] = min(max(h0, 0), HH - 1);  ih2[1] = min(max(h1, 0), HH - 1);
        aww[0] = (w0 >= 0 && w0 < WW) ? (1.f - lw) : 0.f;
        aww[1] = (w1 >= 0 && w1 < WW) ? lw : 0.f;
        iw2[0] = min(max(w0, 0), WW - 1);  iw2[1] = min(max(w1, 0), WW - 1);

#pragma unroll
        for (int ci = 0; ci < 8; ++ci) {
            const int i0 = ci >> 2, i1 = (ci >> 1) & 1, i2 = ci & 1;
            a[ci]  = (it2[i0] * HH + ih2[i1]) * WW + iw2[i2];
            cw[ci] = awt[i0] * awh[i1] * aww[i2];
        }
    };

    auto tap_gather = [&](const int* a, float4* g) {
#pragma unroll
        for (int ci = 0; ci < 8; ++ci)
            g[ci] = *(const float4*)(xn + (size_t)a[ci] * CIN + cgI * 8);
    };

    auto tap_afrag = [&](int k, half8* af) {
#pragma unroll
        for (int ct = 0; ct < 4; ++ct)
            af[ct] = *(const half8*)(wf + (((size_t)k * 4 + ct) * 64 + lane) * 8);
    };

    auto tap_exec = [&](const float4* g, const float* cw, const half8* af) {
        __half2 vacc[4];
#pragma unroll
        for (int j = 0; j < 4; ++j) vacc[j] = __floats2half2_rn(0.f, 0.f);
#pragma unroll
        for (int ci = 0; ci < 8; ++ci) {
            const __half2* uh = (const __half2*)&g[ci];
            const __half2 cw2 = __float2half2_rn(cw[ci]);
            vacc[0] = __hfma2(cw2, uh[0], vacc[0]);
            vacc[1] = __hfma2(cw2, uh[1], vacc[1]);
            vacc[2] = __hfma2(cw2, uh[2], vacc[2]);
            vacc[3] = __hfma2(cw2, uh[3], vacc[3]);
        }
        // repack (pos=lane>>2, ch=lane&3) -> B-frag (pos=lane&15, ch-grp=lane>>4)
        union { __half2 h2[4]; int i[4]; half8 h8; } u, v;
#pragma unroll
        for (int d = 0; d < 4; ++d) u.h2[d] = vacc[d];
#pragma unroll
        for (int d = 0; d < 4; ++d)
            v.i[d] = __builtin_amdgcn_ds_bpermute(bp_addr, u.i[d]);
        const half8 bfrag = v.h8;
#pragma unroll
        for (int ct = 0; ct < 4; ++ct)
            acc[ct] = __builtin_amdgcn_mfma_f32_16x16x32_f16(af[ct], bfrag, acc[ct], 0, 0, 0);
    };

    const int kbeg = half ? KSPLIT : 0;
    const int kend = half ? KK : KSPLIT;

    int    a0[8], a1[8];
    float  cw0[8], cw1[8];
    float4 g0[8], g1[8];
    half8  af0[4], af1[4];

    int k = kbeg;
    for (; k + 1 < kend; k += 2) {
        // both taps' addresses, then BOTH load sets issued back-to-back (2x MLP)
        tap_prep(k, a0, cw0);
        tap_prep(k + 1, a1, cw1);
        tap_gather(a0, g0);
        tap_gather(a1, g1);
        tap_afrag(k, af0);
        tap_afrag(k + 1, af1);
        tap_exec(g0, cw0, af0);
        tap_exec(g1, cw1, af1);
    }
    if (k < kend) {  // odd tail (half 1: 13 taps)
        tap_prep(k, a0, cw0);
        tap_gather(a0, g0);
        tap_afrag(k, af0);
        tap_exec(g0, cw0, af0);
    }

    // LDS reuse boundary: all offset reads done before combine writes
    __syncthreads();
    if (half == 1) {
#pragma unroll
        for (int ct = 0; ct < 4; ++ct)
#pragma unroll
            for (int r = 0; r < 4; ++r) cmb[ct * 4 + r][wpos][lane] = acc[ct][r];
    }
    __syncthreads();
    if (half == 0) {
        // C/D map (16x16): col=lane&15 (pos), row=(lane>>4)*4+reg (co)
#pragma unroll
        for (int ct = 0; ct < 4; ++ct)
#pragma unroll
            for (int r = 0; r < 4; ++r) {
                const int co = ct * 16 + jg * 4 + r;
                out[((size_t)n * COUT + co) * SP + spb + wpos * 16 + (lane & 15)] =
                    acc[ct][r] + cmb[ct * 4 + r][wpos][lane];
            }
    }
}

extern "C" void kernel_launch(void* const* d_in, const int* in_sizes, int n_in,
                              void* d_out, int out_size, void* d_ws, size_t ws_size,
                              hipStream_t stream) {
    const float* x    = (const float*)d_in[0];
    const float* off  = (const float*)d_in[1];
    const float* w    = (const float*)d_in[2];
    const float* bias = (const float*)d_in[3];
    float* out        = (float*)d_out;

    __half* wf  = (__half*)((char*)d_ws + WF_OFF);
    __half* xTh = (__half*)((char*)d_ws + XTH_OFF);

    prep_kernel<<<NBLK + KK, 256, 0, stream>>>(x, w, xTh, wf);
    dconv3d_kernel<<<NBLK, 512, 0, stream>>>(xTh, off, wf, bias, out);
}

// Round 12
// 125.747 us; speedup vs baseline: 1.0095x; 1.0095x over previous
//
#include <hip/hip_runtime.h>
#include <hip/hip_fp16.h>

#define CIN   32
#define COUT  64
#define TT    8
#define HH    56
#define WW    56
#define KK    27
#define SP    (TT * HH * WW)   // 25088
#define NB    2
#define POSB  32
#define NBLK  ((NB * SP) / POSB)   // 1568 main blocks
#define NBLKP 784                  // prep x-transpose blocks (64 pos each)

typedef __attribute__((ext_vector_type(8))) _Float16 half8;
typedef __attribute__((ext_vector_type(4))) float    f32x4;

// d_ws layout
#define WF_OFF   0                    // weight A-frags (16x16x32): 110,592 B
#define XTH_OFF  (128 << 10)          // xTh fp16 channel-last: 3,211,264 B

// prep: blocks [0,784): x [N][C][SP] fp32 -> xTh [N][SP][C] fp16
//       blocks [784,811): weight -> 16x16x32 A-fragments
//       wf[k][ct][lane][j] = w[co = ct*16 + (lane&15)][c = (lane>>4)*8 + j][k]
__global__ __launch_bounds__(256) void prep_kernel(const float* __restrict__ x,
                                                   const float* __restrict__ w,
                                                   __half* __restrict__ xTh,
                                                   __half* __restrict__ wf) {
    const int b = blockIdx.x;
    const int t = threadIdx.x;
    if (b < NBLKP) {
        __shared__ float sm[CIN][65];
        const int s0 = b * 64, n = s0 / SP, sp0 = s0 % SP;
#pragma unroll
        for (int it = 0; it < 8; ++it) {
            const int idx = it * 256 + t, c = idx >> 6, l = idx & 63;
            sm[c][l] = x[((size_t)n * CIN + c) * SP + sp0 + l];
        }
        __syncthreads();
#pragma unroll
        for (int it = 0; it < 4; ++it) {
            const int idx = it * 256 + t, l = idx >> 4, cp = idx & 15;
            ((__half2*)xTh)[((size_t)n * SP + sp0 + l) * (CIN / 2) + cp] =
                __floats2half2_rn(sm[2 * cp][l], sm[2 * cp + 1][l]);
        }
    } else {
        const int k = b - NBLKP;       // 2048 elements: [ct(4)][lane(64)][j(8)]
#pragma unroll
        for (int it = 0; it < 8; ++it) {
            const int idx  = it * 256 + t;
            const int j    = idx & 7;
            const int lane = (idx >> 3) & 63;
            const int ct   = (idx >> 9) & 3;
            const int co   = ct * 16 + (lane & 15);
            const int c    = (lane >> 4) * 8 + j;
            wf[(((size_t)k * 4 + ct) * 64 + lane) * 8 + j] =
                __float2half(w[((size_t)co * CIN + c) * KK + k]);
        }
    }
}

// 512-thread blocks = 2 position-tiles (16 pos) x 4 tap-quarters.
// Grid 1568 -> 4 resident blocks/CU = 32 waves/CU (chip max) for latency hiding.
// Offsets LDS-staged; quad-aligned gathers; bpermute B-frag repack;
// 4-way partial combine through LDS at the end.
__global__ __launch_bounds__(512, 8) void dconv3d_kernel(const __half* __restrict__ xTh,
                                                         const float* __restrict__ off,
                                                         const __half* __restrict__ wf,
                                                         const float* __restrict__ bias,
                                                         float* __restrict__ out) {
    // union: offsets [81][32] (10.4 KB) during main loop; combine [3][16][2][64] (24 KB)
    __shared__ __align__(16) char smem[3 * 16 * 2 * 64 * 4];
    float (*offs)[POSB] = reinterpret_cast<float(*)[POSB]>(smem);
    float (*cmb)[16][2][64] = reinterpret_cast<float(*)[16][2][64]>(smem);

    const int t    = threadIdx.x;
    const int lane = t & 63;
    const int wv   = t >> 6;           // 0..7
    const int wpos = wv & 1;           // position-tile (16 positions each)
    const int q    = wv >> 1;          // tap-quarter 0..3

    // interp persona (quad-aligned gathers)
    const int posI = lane >> 2;        // 0..15
    const int cgI  = lane & 3;         // channels cgI*8 .. +7
    // gemm persona (MFMA B/C fixed layout)
    const int jg   = lane >> 4;        // B k-group / C row-group

    // bpermute source lane: src = 4*(lane&15) + (lane>>4); byte addr = src*4
    const int bp_addr = (((lane & 15) << 2) | jg) << 2;

    // XCD-aware swizzle (bijective on 1568): each XCD gets a contiguous run of
    // 196 blocks = 6272 sp; XCD 0-3 -> batch 0, XCD 4-7 -> batch 1 (no crossing)
    const int sb  = (blockIdx.x & 7) * 196 + (blockIdx.x >> 3);
    const int s0  = sb * POSB;
    const int n   = s0 / SP;
    const int spb = s0 % SP;

    // ---- stage offsets: off[n][row][spb..spb+32) -> offs[row][0..32)
    {
        const float* offbase = off + ((size_t)n * (3 * KK)) * SP + spb;
        for (int i = t; i < 81 * 8; i += 512) {
            const int row = i >> 3, qd = i & 7;
            *(float4*)&offs[row][qd * 4] = *(const float4*)(offbase + (size_t)row * SP + qd * 4);
        }
    }
    __syncthreads();

    const int pl = wpos * 16 + posI;   // local position 0..31
    const int sp = spb + pl;
    const int to = sp / (HH * WW);
    const int hw = sp % (HH * WW);
    const int ho = hw / WW;
    const int wo = hw % WW;

    // bias rides in the MFMA C operand (quarter 0 only)
    f32x4 acc[4];
#pragma unroll
    for (int ct = 0; ct < 4; ++ct)
#pragma unroll
        for (int r = 0; r < 4; ++r)
            acc[ct][r] = q ? 0.f : bias[ct * 16 + jg * 4 + r];

    const __half* xn = xTh + (size_t)n * SP * CIN;

    const int kbeg = q * 7;                       // 0,7,14,21
    const int kend = (q == 3) ? KK : kbeg + 7;    // 7,14,21,27

    for (int k = kbeg; k < kend; ++k) {
        const int kt  = k / 9;
        const int khh = (k / 3) % 3;
        const int kww = k % 3;

        const float pt_ = (float)(to - 1 + kt)  + offs[k * 3 + 0][pl];
        const float ph_ = (float)(ho - 1 + khh) + offs[k * 3 + 1][pl];
        const float pw_ = (float)(wo - 1 + kww) + offs[k * 3 + 2][pl];

        const float ft = floorf(pt_), fh = floorf(ph_), fw = floorf(pw_);
        const float lt = pt_ - ft, lh = ph_ - fh, lw = pw_ - fw;
        const int t0 = (int)ft, h0 = (int)fh, w0 = (int)fw;
        const int t1 = t0 + 1, h1 = h0 + 1, w1 = w0 + 1;

        float awt[2], awh[2], aww[2];
        int   it2[2], ih2[2], iw2[2];
        awt[0] = (t0 >= 0 && t0 < TT) ? (1.f - lt) : 0.f;
        awt[1] = (t1 >= 0 && t1 < TT) ? lt : 0.f;
        it2[0] = min(max(t0, 0), TT - 1);  it2[1] = min(max(t1, 0), TT - 1);
        awh[0] = (h0 >= 0 && h0 < HH) ? (1.f - lh) : 0.f;
        awh[1] = (h1 >= 0 && h1 < HH) ? lh : 0.f;
        ih2[0] = min(max(h0, 0), HH - 1);  ih2[1] = min(max(h1, 0), HH - 1);
        aww[0] = (w0 >= 0 && w0 < WW) ? (1.f - lw) : 0.f;
        aww[1] = (w1 >= 0 && w1 < WW) ? lw : 0.f;
        iw2[0] = min(max(w0, 0), WW - 1);  iw2[1] = min(max(w1, 0), WW - 1);

        int   a[8];
        float cw[8];
#pragma unroll
        for (int ci = 0; ci < 8; ++ci) {
            const int i0 = ci >> 2, i1 = (ci >> 1) & 1, i2 = ci & 1;
            a[ci]  = (it2[i0] * HH + ih2[i1]) * WW + iw2[i2];
            cw[ci] = awt[i0] * awh[i1] * aww[i2];
        }

        // gathers: quad-aligned, one 64 B xTh line per corner per quad
        float4 g[8];
#pragma unroll
        for (int ci = 0; ci < 8; ++ci)
            g[ci] = *(const float4*)(xn + (size_t)a[ci] * CIN + cgI * 8);

        __half2 vacc[4];
#pragma unroll
        for (int j = 0; j < 4; ++j) vacc[j] = __floats2half2_rn(0.f, 0.f);
#pragma unroll
        for (int ci = 0; ci < 8; ++ci) {
            const __half2* uh = (const __half2*)&g[ci];
            const __half2 cw2 = __float2half2_rn(cw[ci]);
            vacc[0] = __hfma2(cw2, uh[0], vacc[0]);
            vacc[1] = __hfma2(cw2, uh[1], vacc[1]);
            vacc[2] = __hfma2(cw2, uh[2], vacc[2]);
            vacc[3] = __hfma2(cw2, uh[3], vacc[3]);
        }

        // repack (pos=lane>>2, ch=lane&3) -> B-frag (pos=lane&15, ch-grp=lane>>4)
        union { __half2 h2[4]; int i[4]; half8 h8; } u, v;
#pragma unroll
        for (int d = 0; d < 4; ++d) u.h2[d] = vacc[d];
#pragma unroll
        for (int d = 0; d < 4; ++d)
            v.i[d] = __builtin_amdgcn_ds_bpermute(bp_addr, u.i[d]);
        const half8 bfrag = v.h8;

#pragma unroll
        for (int ct = 0; ct < 4; ++ct) {
            const half8 af = *(const half8*)(wf + (((size_t)k * 4 + ct) * 64 + lane) * 8);
            acc[ct] = __builtin_amdgcn_mfma_f32_16x16x32_f16(af, bfrag, acc[ct], 0, 0, 0);
        }
    }

    // LDS reuse boundary: all offset reads done before combine writes
    __syncthreads();
    if (q != 0) {
#pragma unroll
        for (int ct = 0; ct < 4; ++ct)
#pragma unroll
            for (int r = 0; r < 4; ++r)
                cmb[q - 1][ct * 4 + r][wpos][lane] = acc[ct][r];
    }
    __syncthreads();
    if (q == 0) {
        // C/D map (16x16): col=lane&15 (pos), row=(lane>>4)*4+reg (co)
#pragma unroll
        for (int ct = 0; ct < 4; ++ct)
#pragma unroll
            for (int r = 0; r < 4; ++r) {
                const int co = ct * 16 + jg * 4 + r;
                float v = acc[ct][r];
#pragma unroll
                for (int j = 0; j < 3; ++j) v += cmb[j][ct * 4 + r][wpos][lane];
                out[((size_t)n * COUT + co) * SP + spb + wpos * 16 + (lane & 15)] = v;
            }
    }
}

extern "C" void kernel_launch(void* const* d_in, const int* in_sizes, int n_in,
                              void* d_out, int out_size, void* d_ws, size_t ws_size,
                              hipStream_t stream) {
    const float* x    = (const float*)d_in[0];
    const float* off  = (const float*)d_in[1];
    const float* w    = (const float*)d_in[2];
    const float* bias = (const float*)d_in[3];
    float* out        = (float*)d_out;

    __half* wf  = (__half*)((char*)d_ws + WF_OFF);
    __half* xTh = (__half*)((char*)d_ws + XTH_OFF);

    prep_kernel<<<NBLKP + KK, 256, 0, stream>>>(x, w, xTh, wf);
    dconv3d_kernel<<<NBLK, 512, 0, stream>>>(xTh, off, wf, bias, out);
}